// Round 2
// baseline (212.972 us; speedup 1.0000x reference)
//
#include <hip/hip_runtime.h>

static constexpr int B = 4, S = 1024, D = 512;

// Small per-row scratch in static device memory (avoids any ws_size assumption).
__device__ float g_ydu[B * S];    // Y_s . x_{s+1}
__device__ float g_ydd[B * S];    // Y_s . x_{s-1}
__device__ float g_alpha[B * S];  // x_s . vq
__device__ float g_beta[B * S];   // x_s . vk
__device__ float g_pn[B * S];     // softmax p at (s, s+1)
__device__ float g_pp[B * S];     // softmax p at (s, s-1)
__device__ float g_nup[B * S];    // sqrt(pn[s]*pp[s+1] + 1e-9)  (band value pre-prior)
__device__ float g_L[B * S];      // log(nb_up + 1e-9)
__device__ float g_C[B * S];      // prefix sums: C[j] = sum_{s<j} L[s]
__device__ float g_vq[D];         // Wq @ bk
__device__ float g_vk[D];         // Wk @ bq
__device__ float g_c0[1];         // bq . bk

__device__ __forceinline__ float wred(float v) {
#pragma unroll
  for (int o = 32; o; o >>= 1) v += __shfl_down(v, o, 64);
  return v;
}

// ---------------- 1. LayerNorm (unbiased var, eps on std) ----------------
__global__ __launch_bounds__(256) void k_ln(const float* __restrict__ ctx,
                                            const float* __restrict__ gamma,
                                            const float* __restrict__ beta,
                                            float* __restrict__ X) {
  const int row = blockIdx.x;  // b*S + s
  const int t = threadIdx.x;   // 256 threads, 2 floats each
  const float2 v = reinterpret_cast<const float2*>(ctx + (size_t)row * D)[t];
  __shared__ float red[4];
  float s = wred(v.x + v.y);
  if ((t & 63) == 0) red[t >> 6] = s;
  __syncthreads();
  const float mu = (red[0] + red[1] + red[2] + red[3]) * (1.0f / (float)D);
  const float dx = v.x - mu, dy = v.y - mu;
  __syncthreads();
  float s2 = wred(dx * dx + dy * dy);
  if ((t & 63) == 0) red[t >> 6] = s2;
  __syncthreads();
  const float var = (red[0] + red[1] + red[2] + red[3]) * (1.0f / (float)(D - 1));
  const float inv = 1.0f / (sqrtf(var) + 1e-6f);
  const float2 g = reinterpret_cast<const float2*>(gamma)[t];
  const float2 be = reinterpret_cast<const float2*>(beta)[t];
  float2 o;
  o.x = g.x * dx * inv + be.x;
  o.y = g.y * dy * inv + be.y;
  reinterpret_cast<float2*>(X + (size_t)row * D)[t] = o;
}

// ---------------- 2. Tiled f32 GEMM: C = A @ B (or A @ B^T) ----------------
// BM=BN=64, BK=16, 256 threads, each computes 4x4.
template <int TRANSB>
__global__ __launch_bounds__(256) void k_gemm(const float* __restrict__ A,
                                              const float* __restrict__ Bm,
                                              float* __restrict__ C, int M, int N,
                                              int K) {
  __shared__ float As[16][68];
  __shared__ float Bs[16][68];
  const int bi = blockIdx.y * 64;
  const int bj = blockIdx.x * 64;
  const int tid = threadIdx.x;
  const int tr = tid >> 4;  // 0..15
  const int tc = tid & 15;  // 0..15
  float acc[4][4] = {};
  for (int kk = 0; kk < K; kk += 16) {
    {  // A tile: As[k][m] = A[(bi+m)*K + kk+k]
      const int k = tid & 15, m0 = tid >> 4;
#pragma unroll
      for (int i = 0; i < 4; ++i)
        As[k][m0 + 16 * i] = A[(size_t)(bi + m0 + 16 * i) * K + kk + k];
    }
    if (TRANSB) {  // Bs[k][n] = Bm[(bj+n)*K + kk+k]
      const int k = tid & 15, n0 = tid >> 4;
#pragma unroll
      for (int i = 0; i < 4; ++i)
        Bs[k][n0 + 16 * i] = Bm[(size_t)(bj + n0 + 16 * i) * K + kk + k];
    } else {  // Bs[k][n] = Bm[(kk+k)*N + bj+n]
      const int n = tid & 63, k0 = tid >> 6;
#pragma unroll
      for (int i = 0; i < 4; ++i)
        Bs[k0 + 4 * i][n] = Bm[(size_t)(kk + k0 + 4 * i) * N + bj + n];
    }
    __syncthreads();
#pragma unroll
    for (int k = 0; k < 16; ++k) {
      float a[4];
#pragma unroll
      for (int m = 0; m < 4; ++m) a[m] = As[k][tr + 16 * m];
      const float4 bv = *reinterpret_cast<const float4*>(&Bs[k][tc * 4]);
      const float bb[4] = {bv.x, bv.y, bv.z, bv.w};
#pragma unroll
      for (int m = 0; m < 4; ++m)
#pragma unroll
        for (int n = 0; n < 4; ++n) acc[m][n] += a[m] * bb[n];
    }
    __syncthreads();
  }
#pragma unroll
  for (int m = 0; m < 4; ++m) {
    const float4 o = make_float4(acc[m][0], acc[m][1], acc[m][2], acc[m][3]);
    *reinterpret_cast<float4*>(&C[(size_t)(bi + tr + 16 * m) * N + bj + tc * 4]) = o;
  }
}

// ---------------- 3. bias folds: vq = Wq@bk, vk = Wk@bq, c0 = bq.bk ----------
__global__ __launch_bounds__(256) void k_bias(const float* __restrict__ Wq,
                                              const float* __restrict__ Wk,
                                              const float* __restrict__ bq,
                                              const float* __restrict__ bk) {
  const int wid = threadIdx.x >> 6, lane = threadIdx.x & 63;
  const int i = blockIdx.x * 4 + wid;  // grid 128 -> 512 rows
  float sq = 0.f, sk = 0.f;
  for (int j = lane; j < D; j += 64) {
    sq += Wq[(size_t)i * D + j] * bk[j];
    sk += Wk[(size_t)i * D + j] * bq[j];
  }
  sq = wred(sq);
  sk = wred(sk);
  if (lane == 0) {
    g_vq[i] = sq;
    g_vk[i] = sk;
  }
  if (blockIdx.x == 0 && threadIdx.x < 64) {
    float c = 0.f;
    for (int j = lane; j < D; j += 64) c += bq[j] * bk[j];
    c = wred(c);
    if (lane == 0) g_c0[0] = c;
  }
}

// ---------------- 4. adjacent dots ----------------
__global__ __launch_bounds__(256) void k_dots(const float* __restrict__ X,
                                              const float* __restrict__ Y) {
  const int b = blockIdx.y, s = blockIdx.x, t = threadIdx.x;
  const int row = b * S + s;
  const float* xs = X + (size_t)row * D;
  const float2 yv = reinterpret_cast<const float2*>(Y + (size_t)row * D)[t];
  const float2 xv = reinterpret_cast<const float2*>(xs)[t];
  const float2 vqv = reinterpret_cast<const float2*>(g_vq)[t];
  const float2 vkv = reinterpret_cast<const float2*>(g_vk)[t];
  float du = 0.f, dd = 0.f;
  if (s + 1 < S) {
    const float2 xn = reinterpret_cast<const float2*>(xs + D)[t];
    du = yv.x * xn.x + yv.y * xn.y;
  }
  if (s > 0) {
    const float2 xp = reinterpret_cast<const float2*>(xs - D)[t];
    dd = yv.x * xp.x + yv.y * xp.y;
  }
  float al = xv.x * vqv.x + xv.y * vqv.y;
  float be = xv.x * vkv.x + xv.y * vkv.y;
  du = wred(du); dd = wred(dd); al = wred(al); be = wred(be);
  __shared__ float red[4][4];
  const int wid = t >> 6, lane = t & 63;
  if (lane == 0) {
    red[wid][0] = du; red[wid][1] = dd; red[wid][2] = al; red[wid][3] = be;
  }
  __syncthreads();
  if (t == 0) {
    float a0 = 0, a1 = 0, a2 = 0, a3 = 0;
    for (int i = 0; i < 4; ++i) {
      a0 += red[i][0]; a1 += red[i][1]; a2 += red[i][2]; a3 += red[i][3];
    }
    g_ydu[row] = a0; g_ydd[row] = a1; g_alpha[row] = a2; g_beta[row] = a3;
  }
}

// ---------------- 5. 2-entry band softmax ----------------
__global__ void k_band(const int* __restrict__ eos) {
  const int idx = blockIdx.x * blockDim.x + threadIdx.x;  // b*S + s
  const int b = idx >> 10, s = idx & (S - 1);
  const float c = g_c0[0];
  const bool uv = (s + 1 < S) && (eos[b * S + s + 1] != 0);
  const bool dv = (s >= 1) && (eos[b * S + s - 1] != 0);
  const float su =
      uv ? (g_ydu[idx] + g_alpha[idx] + g_beta[idx + 1] + c) * (1.0f / 256.0f)
         : -1e9f;
  const float sd =
      dv ? (g_ydd[idx] + g_alpha[idx] + g_beta[idx - 1] + c) * (1.0f / 256.0f)
         : -1e9f;
  const float m = fmaxf(su, sd);
  const float eu = expf(su - m), ed = expf(sd - m);
  const float inv = 1.0f / (eu + ed);
  g_pn[idx] = eu * inv;
  g_pp[idx] = ed * inv;
}

// ---------------- 6. band value + log ----------------
__global__ void k_nup(const float* __restrict__ prior) {
  const int idx = blockIdx.x * blockDim.x + threadIdx.x;  // b*S + s
  const int b = idx >> 10, s = idx & (S - 1);
  if (s >= S - 1) {
    g_nup[idx] = 0.f;
    g_L[idx] = 0.f;
    return;
  }
  const float v = sqrtf(g_pn[idx] * g_pp[idx + 1] + 1e-9f);
  const float pr = prior[((size_t)b * S + s) * S + s + 1];
  const float nb = pr + (1.0f - pr) * v;
  g_nup[idx] = v;
  g_L[idx] = logf(nb + 1e-9f);
}

// ---------------- 7. per-batch prefix scan: C[j] = sum_{s<j} L[s] ------------
__global__ __launch_bounds__(1024) void k_scan() {
  const int b = blockIdx.x, t = threadIdx.x;
  __shared__ float sh[S];
  sh[t] = (t > 0) ? g_L[b * S + t - 1] : 0.0f;
  __syncthreads();
  for (int o = 1; o < S; o <<= 1) {
    const float add = (t >= o) ? sh[t - o] : 0.0f;
    __syncthreads();
    sh[t] += add;
    __syncthreads();
  }
  g_C[b * S + t] = sh[t];
}

// ---------------- 8. final outputs ----------------
__global__ __launch_bounds__(256) void k_final(const float* __restrict__ prior,
                                               float* __restrict__ out0,
                                               float* __restrict__ out1) {
  const int b = blockIdx.y, i = blockIdx.x, t = threadIdx.x;
  const size_t rowoff = ((size_t)b * S + i) * S;
  const float4 pr4 = reinterpret_cast<const float4*>(prior + rowoff)[t];
  const float4 cj4 = reinterpret_cast<const float4*>(g_C + b * S)[t];
  const float ci = g_C[b * S + i];
  const float SQ = sqrtf(1e-9f);
  const float prr[4] = {pr4.x, pr4.y, pr4.z, pr4.w};
  const float cjj[4] = {cj4.x, cj4.y, cj4.z, cj4.w};
  float o0[4], o1[4];
#pragma unroll
  for (int q = 0; q < 4; ++q) {
    const int j = t * 4 + q;
    const float p = prr[q];
    float v;
    if (j == i + 1) v = g_nup[b * S + i];
    else if (j == i - 1) v = g_nup[b * S + j];
    else v = SQ;
    o1[q] = p + (1.0f - p) * v;
    if (j == i) {
      o0[q] = p + (1.0f - p) * SQ;  // diag: neibor_attn[i,i]
    } else {
      const float d = (j > i) ? (cjj[q] - ci) : (ci - cjj[q]);
      o0[q] = expf(d) + 1e-9f;
    }
  }
  reinterpret_cast<float4*>(out0 + rowoff)[t] =
      make_float4(o0[0], o0[1], o0[2], o0[3]);
  reinterpret_cast<float4*>(out1 + rowoff)[t] =
      make_float4(o1[0], o1[1], o1[2], o1[3]);
}

extern "C" void kernel_launch(void* const* d_in, const int* in_sizes, int n_in,
                              void* d_out, int out_size, void* d_ws,
                              size_t ws_size, hipStream_t stream) {
  (void)in_sizes; (void)n_in; (void)out_size; (void)d_ws; (void)ws_size;
  const float* ctx = (const float*)d_in[0];
  const float* prior = (const float*)d_in[1];
  const float* Wq = (const float*)d_in[2];
  const float* bq = (const float*)d_in[3];
  const float* Wk = (const float*)d_in[4];
  const float* bk = (const float*)d_in[5];
  const float* gamma = (const float*)d_in[6];
  const float* beta = (const float*)d_in[7];
  const int* eos = (const int*)d_in[8];

  float* ob = (float*)d_out;
  float* out0 = ob;                              // [B,S,S]
  float* out1 = ob + (size_t)B * S * S;          // [B,S,S]
  // Scratch staged inside d_out; all consumed before k_final writes outputs.
  float* X = ob;                                 // 2M floats (LN output)
  float* Y = ob + 2097152;                       // 2M floats (X @ M)
  float* Mm = ob + 4194304;                      // 256K floats (Wq @ Wk^T)

  k_ln<<<B * S, 256, 0, stream>>>(ctx, gamma, beta, X);
  k_gemm<1><<<dim3(8, 8), 256, 0, stream>>>(Wq, Wk, Mm, D, D, D);
  k_bias<<<128, 256, 0, stream>>>(Wq, Wk, bq, bk);
  k_gemm<0><<<dim3(8, 64), 256, 0, stream>>>(X, Mm, Y, B * S, D, D);
  k_dots<<<dim3(S, B), 256, 0, stream>>>(X, Y);
  k_band<<<16, 256, 0, stream>>>(eos);
  k_nup<<<16, 256, 0, stream>>>(prior);
  k_scan<<<B, 1024, 0, stream>>>();
  k_final<<<dim3(S, B), 256, 0, stream>>>(prior, out0, out1);
}

// Round 4
// 138.339 us; speedup vs baseline: 1.5395x; 1.5395x over previous
//
#include <hip/hip_runtime.h>

static constexpr int B = 4, S = 1024, D = 512;

typedef __attribute__((ext_vector_type(8))) short short8;
typedef __attribute__((ext_vector_type(4))) float f32x4;

// Small per-row scratch in static device memory.
__device__ float g_ydu[B * S];    // Y_s . x_{s+1}
__device__ float g_ydd[B * S];    // Y_s . x_{s-1}
__device__ float g_alpha[B * S];  // x_s . vq
__device__ float g_beta[B * S];   // x_s . vk
__device__ float g_nup[B * S];    // sqrt(pn[s]*pp[s+1] + 1e-9)
__device__ float g_C[B * S];      // prefix sums of L
__device__ float g_vq[D];         // Wq @ bk
__device__ float g_vk[D];         // Wk @ bq
__device__ float g_c0[1];         // bq . bk

__device__ __forceinline__ float wred(float v) {
#pragma unroll
  for (int o = 32; o; o >>= 1) v += __shfl_down(v, o, 64);
  return v;
}

__device__ __forceinline__ ushort f2bf(float f) {
  union { float f; unsigned u; } x;
  x.f = f;
  unsigned r = x.u + 0x7fffu + ((x.u >> 16) & 1u);  // RNE
  return (ushort)(r >> 16);
}
__device__ __forceinline__ float bf2f(ushort u) {
  union { unsigned u; float f; } x;
  x.u = ((unsigned)u) << 16;
  return x.f;
}

// ---------------- 1. LayerNorm -> bf16 X ----------------
__global__ __launch_bounds__(256) void k_ln(const float* __restrict__ ctx,
                                            const float* __restrict__ gamma,
                                            const float* __restrict__ beta,
                                            unsigned* __restrict__ Xb /*packed bf16x2*/) {
  const int row = blockIdx.x;  // b*S + s
  const int t = threadIdx.x;   // 256 threads, 2 floats each
  const float2 v = reinterpret_cast<const float2*>(ctx + (size_t)row * D)[t];
  __shared__ float red[4];
  float s = wred(v.x + v.y);
  if ((t & 63) == 0) red[t >> 6] = s;
  __syncthreads();
  const float mu = (red[0] + red[1] + red[2] + red[3]) * (1.0f / (float)D);
  const float dx = v.x - mu, dy = v.y - mu;
  __syncthreads();
  float s2 = wred(dx * dx + dy * dy);
  if ((t & 63) == 0) red[t >> 6] = s2;
  __syncthreads();
  const float var = (red[0] + red[1] + red[2] + red[3]) * (1.0f / (float)(D - 1));
  const float inv = 1.0f / (sqrtf(var) + 1e-6f);
  const float2 g = reinterpret_cast<const float2*>(gamma)[t];
  const float2 be = reinterpret_cast<const float2*>(beta)[t];
  const float ox = g.x * dx * inv + be.x;
  const float oy = g.y * dy * inv + be.y;
  Xb[(size_t)row * (D / 2) + t] = (unsigned)f2bf(ox) | ((unsigned)f2bf(oy) << 16);
}

// ---------------- 2. MFMA GEMM: C[64x64 tile] = A @ B^T ----------------
// A: [M][K], B: [N][K]; both K-contiguous rows. SRC_F32: convert on stage.
// 256 thr = 4 waves; wave w owns 32x32 quadrant; acc[2][2] of 16x16 tiles.
template <int SRC_F32, int OUT_BF16>
__global__ __launch_bounds__(256) void k_mfma_gemm(const void* __restrict__ Ap,
                                                   const void* __restrict__ Bp,
                                                   void* __restrict__ Cp, int K,
                                                   int ldc) {
  __shared__ __align__(16) short As[64 * 64];
  __shared__ __align__(16) short Bs[64 * 64];
  const int tid = threadIdx.x;
  const int bi = blockIdx.y * 64, bj = blockIdx.x * 64;
  const int w = tid >> 6, l = tid & 63;
  const int wr = (w >> 1) * 32, wc = (w & 1) * 32;
  const int lrow = l & 15, lgrp = l >> 4;
  const int srow = tid >> 2;         // staging row 0..63
  const int schunk = (tid & 3) * 2;  // chunk = 8 bf16 = 16B; each thread 2 chunks
  f32x4 acc[2][2] = {};

  for (int kk = 0; kk < K; kk += 64) {
    short8 va0, va1, vb0, vb1;
    if constexpr (SRC_F32) {
      const float* sa = (const float*)Ap + (size_t)(bi + srow) * K + kk + schunk * 8;
      const float* sb = (const float*)Bp + (size_t)(bj + srow) * K + kk + schunk * 8;
#pragma unroll
      for (int i = 0; i < 2; ++i) {
        const float4 a0 = reinterpret_cast<const float4*>(sa)[2 * i];
        const float4 a1 = reinterpret_cast<const float4*>(sa)[2 * i + 1];
        const float4 b0 = reinterpret_cast<const float4*>(sb)[2 * i];
        const float4 b1 = reinterpret_cast<const float4*>(sb)[2 * i + 1];
        short8* pa = i ? &va1 : &va0;
        short8* pb = i ? &vb1 : &vb0;
        (*pa)[0] = (short)f2bf(a0.x); (*pa)[1] = (short)f2bf(a0.y);
        (*pa)[2] = (short)f2bf(a0.z); (*pa)[3] = (short)f2bf(a0.w);
        (*pa)[4] = (short)f2bf(a1.x); (*pa)[5] = (short)f2bf(a1.y);
        (*pa)[6] = (short)f2bf(a1.z); (*pa)[7] = (short)f2bf(a1.w);
        (*pb)[0] = (short)f2bf(b0.x); (*pb)[1] = (short)f2bf(b0.y);
        (*pb)[2] = (short)f2bf(b0.z); (*pb)[3] = (short)f2bf(b0.w);
        (*pb)[4] = (short)f2bf(b1.x); (*pb)[5] = (short)f2bf(b1.y);
        (*pb)[6] = (short)f2bf(b1.z); (*pb)[7] = (short)f2bf(b1.w);
      }
    } else {
      const short* sa = (const short*)Ap + (size_t)(bi + srow) * K + kk + schunk * 8;
      const short* sb = (const short*)Bp + (size_t)(bj + srow) * K + kk + schunk * 8;
      va0 = reinterpret_cast<const short8*>(sa)[0];
      va1 = reinterpret_cast<const short8*>(sa)[1];
      vb0 = reinterpret_cast<const short8*>(sb)[0];
      vb1 = reinterpret_cast<const short8*>(sb)[1];
    }
    const int sw = srow & 7;
    *reinterpret_cast<short8*>(&As[srow * 64 + ((schunk ^ sw) << 3)]) = va0;
    *reinterpret_cast<short8*>(&As[srow * 64 + (((schunk + 1) ^ sw) << 3)]) = va1;
    *reinterpret_cast<short8*>(&Bs[srow * 64 + ((schunk ^ sw) << 3)]) = vb0;
    *reinterpret_cast<short8*>(&Bs[srow * 64 + (((schunk + 1) ^ sw) << 3)]) = vb1;
    __syncthreads();
#pragma unroll
    for (int ks = 0; ks < 2; ++ks) {
      short8 af[2], bfr[2];
#pragma unroll
      for (int mi = 0; mi < 2; ++mi) {
        const int r = wr + 16 * mi + lrow;
        af[mi] = *reinterpret_cast<const short8*>(
            &As[r * 64 + (((ks * 4 + lgrp) ^ (r & 7)) << 3)]);
      }
#pragma unroll
      for (int ni = 0; ni < 2; ++ni) {
        const int r = wc + 16 * ni + lrow;
        bfr[ni] = *reinterpret_cast<const short8*>(
            &Bs[r * 64 + (((ks * 4 + lgrp) ^ (r & 7)) << 3)]);
      }
#pragma unroll
      for (int mi = 0; mi < 2; ++mi)
#pragma unroll
        for (int ni = 0; ni < 2; ++ni)
          acc[mi][ni] = __builtin_amdgcn_mfma_f32_16x16x32_bf16(
              af[mi], bfr[ni], acc[mi][ni], 0, 0, 0);
    }
    __syncthreads();
  }
  // C/D layout (m89): col = lane&15, row = (lane>>4)*4 + reg
#pragma unroll
  for (int mi = 0; mi < 2; ++mi)
#pragma unroll
    for (int ni = 0; ni < 2; ++ni)
#pragma unroll
      for (int v = 0; v < 4; ++v) {
        const int r = bi + wr + 16 * mi + lgrp * 4 + v;
        const int c = bj + wc + 16 * ni + lrow;
        if constexpr (OUT_BF16)
          ((ushort*)Cp)[(size_t)r * ldc + c] = f2bf(acc[mi][ni][v]);
        else
          ((float*)Cp)[(size_t)r * ldc + c] = acc[mi][ni][v];
      }
}

// ---------------- 3. bias folds ----------------
__global__ __launch_bounds__(256) void k_bias(const float* __restrict__ Wq,
                                              const float* __restrict__ Wk,
                                              const float* __restrict__ bq,
                                              const float* __restrict__ bk) {
  const int wid = threadIdx.x >> 6, lane = threadIdx.x & 63;
  const int i = blockIdx.x * 4 + wid;
  float sq = 0.f, sk = 0.f;
  for (int j = lane; j < D; j += 64) {
    sq += Wq[(size_t)i * D + j] * bk[j];
    sk += Wk[(size_t)i * D + j] * bq[j];
  }
  sq = wred(sq);
  sk = wred(sk);
  if (lane == 0) {
    g_vq[i] = sq;
    g_vk[i] = sk;
  }
  if (blockIdx.x == 0 && threadIdx.x < 64) {
    float c = 0.f;
    for (int j = lane; j < D; j += 64) c += bq[j] * bk[j];
    c = wred(c);
    if (lane == 0) g_c0[0] = c;
  }
}

// ---------------- 4. adjacent dots (Xb bf16, Y f32) ----------------
__global__ __launch_bounds__(256) void k_dots(const unsigned* __restrict__ Xb,
                                              const float* __restrict__ Y) {
  const int b = blockIdx.y, s = blockIdx.x, t = threadIdx.x;
  const int row = b * S + s;
  const unsigned* xs = Xb + (size_t)row * (D / 2);
  const float2 yv = reinterpret_cast<const float2*>(Y + (size_t)row * D)[t];
  const unsigned xp0 = xs[t];
  const float2 vqv = reinterpret_cast<const float2*>(g_vq)[t];
  const float2 vkv = reinterpret_cast<const float2*>(g_vk)[t];
  float du = 0.f, dd = 0.f;
  if (s + 1 < S) {
    const unsigned xn = xs[D / 2 + t];
    du = yv.x * bf2f((ushort)(xn & 0xffff)) + yv.y * bf2f((ushort)(xn >> 16));
  }
  if (s > 0) {
    const unsigned xq = xs[t - D / 2];
    dd = yv.x * bf2f((ushort)(xq & 0xffff)) + yv.y * bf2f((ushort)(xq >> 16));
  }
  const float x0 = bf2f((ushort)(xp0 & 0xffff)), x1 = bf2f((ushort)(xp0 >> 16));
  float al = x0 * vqv.x + x1 * vqv.y;
  float be = x0 * vkv.x + x1 * vkv.y;
  du = wred(du); dd = wred(dd); al = wred(al); be = wred(be);
  __shared__ float red[4][4];
  const int wid = t >> 6, lane = t & 63;
  if (lane == 0) {
    red[wid][0] = du; red[wid][1] = dd; red[wid][2] = al; red[wid][3] = be;
  }
  __syncthreads();
  if (t == 0) {
    float a0 = 0, a1 = 0, a2 = 0, a3 = 0;
    for (int i = 0; i < 4; ++i) {
      a0 += red[i][0]; a1 += red[i][1]; a2 += red[i][2]; a3 += red[i][3];
    }
    g_ydu[row] = a0; g_ydd[row] = a1; g_alpha[row] = a2; g_beta[row] = a3;
  }
}

// ---------------- 5. fused band-softmax + band value + scan ----------------
__global__ __launch_bounds__(1024) void k_smscan(const int* __restrict__ eos,
                                                 const float* __restrict__ prior) {
  const int b = blockIdx.x, s = threadIdx.x;
  const int idx = b * S + s;
  __shared__ float spp[S];
  __shared__ float sh[S];
  const float c = g_c0[0];
  const bool uv = (s + 1 < S) && (eos[b * S + s + 1] != 0);
  const bool dv = (s >= 1) && (eos[b * S + s - 1] != 0);
  const float su =
      uv ? (g_ydu[idx] + g_alpha[idx] + g_beta[idx + 1] + c) * (1.0f / 256.0f)
         : -1e9f;
  const float sd =
      dv ? (g_ydd[idx] + g_alpha[idx] + g_beta[idx - 1] + c) * (1.0f / 256.0f)
         : -1e9f;
  const float m = fmaxf(su, sd);
  const float eu = expf(su - m), ed = expf(sd - m);
  const float inv = 1.0f / (eu + ed);
  const float pn = eu * inv, pp = ed * inv;
  spp[s] = pp;
  __syncthreads();
  float v = 0.f, L = 0.f;
  if (s < S - 1) {
    v = sqrtf(pn * spp[s + 1] + 1e-9f);
    const float pr = prior[((size_t)b * S + s) * S + s + 1];
    L = logf(pr + (1.0f - pr) * v + 1e-9f);
  }
  g_nup[idx] = v;
  __syncthreads();     // all spp reads done
  spp[s] = L;          // reuse as L buffer
  __syncthreads();
  sh[s] = (s > 0) ? spp[s - 1] : 0.0f;
  __syncthreads();
  for (int o = 1; o < S; o <<= 1) {
    const float add = (s >= o) ? sh[s - o] : 0.0f;
    __syncthreads();
    sh[s] += add;
    __syncthreads();
  }
  g_C[idx] = sh[s];
}

// ---------------- 6. final outputs ----------------
__global__ __launch_bounds__(256) void k_final(const float* __restrict__ prior,
                                               float* __restrict__ out0,
                                               float* __restrict__ out1) {
  const int b = blockIdx.y, i = blockIdx.x, t = threadIdx.x;
  const size_t rowoff = ((size_t)b * S + i) * S;
  const float4 pr4 = reinterpret_cast<const float4*>(prior + rowoff)[t];
  const float4 cj4 = reinterpret_cast<const float4*>(g_C + b * S)[t];
  const float ci = g_C[b * S + i];
  const float SQ = sqrtf(1e-9f);
  const float prr[4] = {pr4.x, pr4.y, pr4.z, pr4.w};
  const float cjj[4] = {cj4.x, cj4.y, cj4.z, cj4.w};
  float o0[4], o1[4];
#pragma unroll
  for (int q = 0; q < 4; ++q) {
    const int j = t * 4 + q;
    const float p = prr[q];
    float v;
    if (j == i + 1) v = g_nup[b * S + i];
    else if (j == i - 1) v = g_nup[b * S + j];
    else v = SQ;
    o1[q] = p + (1.0f - p) * v;
    if (j == i) {
      o0[q] = p + (1.0f - p) * SQ;
    } else {
      const float d = (j > i) ? (cjj[q] - ci) : (ci - cjj[q]);
      o0[q] = expf(d) + 1e-9f;
    }
  }
  reinterpret_cast<float4*>(out0 + rowoff)[t] =
      make_float4(o0[0], o0[1], o0[2], o0[3]);
  reinterpret_cast<float4*>(out1 + rowoff)[t] =
      make_float4(o1[0], o1[1], o1[2], o1[3]);
}

extern "C" void kernel_launch(void* const* d_in, const int* in_sizes, int n_in,
                              void* d_out, int out_size, void* d_ws,
                              size_t ws_size, hipStream_t stream) {
  (void)in_sizes; (void)n_in; (void)out_size; (void)d_ws; (void)ws_size;
  const float* ctx = (const float*)d_in[0];
  const float* prior = (const float*)d_in[1];
  const float* Wq = (const float*)d_in[2];
  const float* bq = (const float*)d_in[3];
  const float* Wk = (const float*)d_in[4];
  const float* bk = (const float*)d_in[5];
  const float* gamma = (const float*)d_in[6];
  const float* beta = (const float*)d_in[7];
  const int* eos = (const int*)d_in[8];

  float* ob = (float*)d_out;
  float* out0 = ob;                      // [B,S,S]
  float* out1 = ob + (size_t)B * S * S;  // [B,S,S]
  // Scratch staged inside d_out; all consumed before k_final writes outputs.
  unsigned* Xb = (unsigned*)ob;          // bf16 X, 2M elems = 4MB (floats [0,1M))
  ushort* Mt = (ushort*)(ob + 1048576);  // bf16 Mt=Wk@Wq^T, 256K elems (floats [1M,1.125M))
  float* Y = ob + 2097152;               // f32 Y = X@M, 2M floats (floats [2M,4M))

  k_ln<<<B * S, 256, 0, stream>>>(ctx, gamma, beta, Xb);
  // Mt[n][k] = sum_t Wk[n,t]*Wq[k,t]  (= (Wq@Wk^T) transposed, K-major rows)
  k_mfma_gemm<1, 1><<<dim3(8, 8), 256, 0, stream>>>(Wk, Wq, Mt, D, D);
  k_bias<<<128, 256, 0, stream>>>(Wq, Wk, bq, bk);
  // Y[r][n] = sum_k Xb[r,k]*Mt[n,k]
  k_mfma_gemm<0, 0><<<dim3(8, 64), 256, 0, stream>>>(Xb, Mt, Y, D, D);
  k_dots<<<dim3(S, B), 256, 0, stream>>>(Xb, Y);
  k_smscan<<<B, 1024, 0, stream>>>(eos, prior);
  k_final<<<dim3(S, B), 256, 0, stream>>>(prior, out0, out1);
}

// Round 5
// 132.506 us; speedup vs baseline: 1.6073x; 1.0440x over previous
//
#include <hip/hip_runtime.h>

static constexpr int B = 4, S = 1024, D = 512;

typedef __attribute__((ext_vector_type(8))) short short8;
typedef __attribute__((ext_vector_type(4))) float f32x4;

// Static device scratch.
__device__ float g_alpha[B * S];        // x_s . vq  (f32 LN output)
__device__ float g_beta[B * S];         // x_s . vk
__device__ float g_nup[B * S];          // sqrt(pn[s]*pp[s+1] + 1e-9)
__device__ float g_C[B * S];            // prefix sums of L
__device__ float g_tupart[16][B * S];   // partial Y_s.x_{s+1}, slot = nb*2 + wave-col
__device__ float g_tdpart[16][B * S];   // partial Y_s.x_{s-1}
__device__ float g_vq[D];               // Wq @ bk
__device__ float g_vk[D];               // Wk @ bq
__device__ float g_c0[1];               // bq . bk

__device__ __forceinline__ float wred(float v) {
#pragma unroll
  for (int o = 32; o; o >>= 1) v += __shfl_down(v, o, 64);
  return v;
}

__device__ __forceinline__ ushort f2bf(float f) {
  union { float f; unsigned u; } x;
  x.f = f;
  unsigned r = x.u + 0x7fffu + ((x.u >> 16) & 1u);  // RNE
  return (ushort)(r >> 16);
}
__device__ __forceinline__ float bf2f(ushort u) {
  union { unsigned u; float f; } x;
  x.u = ((unsigned)u) << 16;
  return x.f;
}

// ---------------- 1. bias folds: vq, vk, c0 ----------------
__global__ __launch_bounds__(256) void k_bias(const float* __restrict__ Wq,
                                              const float* __restrict__ Wk,
                                              const float* __restrict__ bq,
                                              const float* __restrict__ bk) {
  const int wid = threadIdx.x >> 6, lane = threadIdx.x & 63;
  const int i = blockIdx.x * 4 + wid;
  float sq = 0.f, sk = 0.f;
  for (int j = lane; j < D; j += 64) {
    sq += Wq[(size_t)i * D + j] * bk[j];
    sk += Wk[(size_t)i * D + j] * bq[j];
  }
  sq = wred(sq);
  sk = wred(sk);
  if (lane == 0) {
    g_vq[i] = sq;
    g_vk[i] = sk;
  }
  if (blockIdx.x == 0 && threadIdx.x < 64) {
    float c = 0.f;
    for (int j = lane; j < D; j += 64) c += bq[j] * bk[j];
    c = wred(c);
    if (lane == 0) g_c0[0] = c;
  }
}

// ---------------- 2. LayerNorm -> bf16 X, plus alpha/beta ----------------
__global__ __launch_bounds__(256) void k_ln(const float* __restrict__ ctx,
                                            const float* __restrict__ gamma,
                                            const float* __restrict__ beta,
                                            unsigned* __restrict__ Xb) {
  const int row = blockIdx.x;  // b*S + s
  const int t = threadIdx.x;
  const float2 v = reinterpret_cast<const float2*>(ctx + (size_t)row * D)[t];
  __shared__ float red[4];
  __shared__ float red2[4][2];
  float s = wred(v.x + v.y);
  if ((t & 63) == 0) red[t >> 6] = s;
  __syncthreads();
  const float mu = (red[0] + red[1] + red[2] + red[3]) * (1.0f / (float)D);
  const float dx = v.x - mu, dy = v.y - mu;
  __syncthreads();
  float s2 = wred(dx * dx + dy * dy);
  if ((t & 63) == 0) red[t >> 6] = s2;
  __syncthreads();
  const float var = (red[0] + red[1] + red[2] + red[3]) * (1.0f / (float)(D - 1));
  const float inv = 1.0f / (sqrtf(var) + 1e-6f);
  const float2 g = reinterpret_cast<const float2*>(gamma)[t];
  const float2 be = reinterpret_cast<const float2*>(beta)[t];
  const float ox = g.x * dx * inv + be.x;
  const float oy = g.y * dy * inv + be.y;
  Xb[(size_t)row * (D / 2) + t] = (unsigned)f2bf(ox) | ((unsigned)f2bf(oy) << 16);
  // alpha/beta with f32 LN output
  const float2 vqv = reinterpret_cast<const float2*>(g_vq)[t];
  const float2 vkv = reinterpret_cast<const float2*>(g_vk)[t];
  float al = wred(ox * vqv.x + oy * vqv.y);
  float bb = wred(ox * vkv.x + oy * vkv.y);
  const int wid = t >> 6, lane = t & 63;
  if (lane == 0) { red2[wid][0] = al; red2[wid][1] = bb; }
  __syncthreads();
  if (t == 0) {
    g_alpha[row] = red2[0][0] + red2[1][0] + red2[2][0] + red2[3][0];
    g_beta[row]  = red2[0][1] + red2[1][1] + red2[2][1] + red2[3][1];
  }
}

// ---------------- 3. MFMA GEMM (f32 src -> bf16 out): Mt = Wk @ Wq^T --------
__global__ __launch_bounds__(256) void k_gemm_m(const float* __restrict__ Ap,
                                                const float* __restrict__ Bp,
                                                ushort* __restrict__ Cp) {
  __shared__ __align__(16) short As[64 * 64];
  __shared__ __align__(16) short Bs[64 * 64];
  const int tid = threadIdx.x;
  const int bi = blockIdx.y * 64, bj = blockIdx.x * 64;
  const int w = tid >> 6, l = tid & 63;
  const int wr = (w >> 1) * 32, wc = (w & 1) * 32;
  const int lrow = l & 15, lgrp = l >> 4;
  const int srow = tid >> 2, schunk = (tid & 3) * 2;
  f32x4 acc[2][2] = {};
  for (int kk = 0; kk < D; kk += 64) {
    short8 va0, va1, vb0, vb1;
    const float* sa = Ap + (size_t)(bi + srow) * D + kk + schunk * 8;
    const float* sb = Bp + (size_t)(bj + srow) * D + kk + schunk * 8;
#pragma unroll
    for (int i = 0; i < 2; ++i) {
      const float4 a0 = reinterpret_cast<const float4*>(sa)[2 * i];
      const float4 a1 = reinterpret_cast<const float4*>(sa)[2 * i + 1];
      const float4 b0 = reinterpret_cast<const float4*>(sb)[2 * i];
      const float4 b1 = reinterpret_cast<const float4*>(sb)[2 * i + 1];
      short8* pa = i ? &va1 : &va0;
      short8* pb = i ? &vb1 : &vb0;
      (*pa)[0] = (short)f2bf(a0.x); (*pa)[1] = (short)f2bf(a0.y);
      (*pa)[2] = (short)f2bf(a0.z); (*pa)[3] = (short)f2bf(a0.w);
      (*pa)[4] = (short)f2bf(a1.x); (*pa)[5] = (short)f2bf(a1.y);
      (*pa)[6] = (short)f2bf(a1.z); (*pa)[7] = (short)f2bf(a1.w);
      (*pb)[0] = (short)f2bf(b0.x); (*pb)[1] = (short)f2bf(b0.y);
      (*pb)[2] = (short)f2bf(b0.z); (*pb)[3] = (short)f2bf(b0.w);
      (*pb)[4] = (short)f2bf(b1.x); (*pb)[5] = (short)f2bf(b1.y);
      (*pb)[6] = (short)f2bf(b1.z); (*pb)[7] = (short)f2bf(b1.w);
    }
    const int sw = srow & 7;
    *reinterpret_cast<short8*>(&As[srow * 64 + ((schunk ^ sw) << 3)]) = va0;
    *reinterpret_cast<short8*>(&As[srow * 64 + (((schunk + 1) ^ sw) << 3)]) = va1;
    *reinterpret_cast<short8*>(&Bs[srow * 64 + ((schunk ^ sw) << 3)]) = vb0;
    *reinterpret_cast<short8*>(&Bs[srow * 64 + (((schunk + 1) ^ sw) << 3)]) = vb1;
    __syncthreads();
#pragma unroll
    for (int ks = 0; ks < 2; ++ks) {
      short8 af[2], bfr[2];
#pragma unroll
      for (int mi = 0; mi < 2; ++mi) {
        const int r = wr + 16 * mi + lrow;
        af[mi] = *reinterpret_cast<const short8*>(
            &As[r * 64 + (((ks * 4 + lgrp) ^ (r & 7)) << 3)]);
      }
#pragma unroll
      for (int ni = 0; ni < 2; ++ni) {
        const int r = wc + 16 * ni + lrow;
        bfr[ni] = *reinterpret_cast<const short8*>(
            &Bs[r * 64 + (((ks * 4 + lgrp) ^ (r & 7)) << 3)]);
      }
#pragma unroll
      for (int mi = 0; mi < 2; ++mi)
#pragma unroll
        for (int ni = 0; ni < 2; ++ni)
          acc[mi][ni] = __builtin_amdgcn_mfma_f32_16x16x32_bf16(
              af[mi], bfr[ni], acc[mi][ni], 0, 0, 0);
    }
    __syncthreads();
  }
#pragma unroll
  for (int mi = 0; mi < 2; ++mi)
#pragma unroll
    for (int ni = 0; ni < 2; ++ni)
#pragma unroll
      for (int v = 0; v < 4; ++v) {
        const int r = bi + wr + 16 * mi + lgrp * 4 + v;
        const int c = bj + wc + 16 * ni + lrow;
        Cp[(size_t)r * D + c] = f2bf(acc[mi][ni][v]);
      }
}

// ------- 4. fused band-dot: Y chunk in regs, dot with x_{s±1}, partials -----
// grid (64 s-blocks, 8 n-blocks). Block: Y_chunk[64 rows][64 cols] via MFMA,
// tu/td partials -> g_t{u,d}part[nb*2 + wave-col][row].
__global__ __launch_bounds__(256) void k_banddot(const ushort* __restrict__ Xb2,
                                                 const ushort* __restrict__ Mt) {
  __shared__ __align__(16) short As[64 * 64];
  __shared__ __align__(16) short Bs[64 * 64];
  const int tid = threadIdx.x;
  const int r0 = blockIdx.x * 64, n0 = blockIdx.y * 64;
  const int w = tid >> 6, l = tid & 63;
  const int wr = (w >> 1) * 32, wc = (w & 1) * 32;
  const int lrow = l & 15, lgrp = l >> 4;
  const int srow = tid >> 2, schunk = (tid & 3) * 2;
  f32x4 acc[2][2] = {};
  for (int kk = 0; kk < D; kk += 64) {
    const short* sa = (const short*)Xb2 + (size_t)(r0 + srow) * D + kk + schunk * 8;
    const short* sb = (const short*)Mt + (size_t)(n0 + srow) * D + kk + schunk * 8;
    short8 va0 = reinterpret_cast<const short8*>(sa)[0];
    short8 va1 = reinterpret_cast<const short8*>(sa)[1];
    short8 vb0 = reinterpret_cast<const short8*>(sb)[0];
    short8 vb1 = reinterpret_cast<const short8*>(sb)[1];
    const int sw = srow & 7;
    *reinterpret_cast<short8*>(&As[srow * 64 + ((schunk ^ sw) << 3)]) = va0;
    *reinterpret_cast<short8*>(&As[srow * 64 + (((schunk + 1) ^ sw) << 3)]) = va1;
    *reinterpret_cast<short8*>(&Bs[srow * 64 + ((schunk ^ sw) << 3)]) = vb0;
    *reinterpret_cast<short8*>(&Bs[srow * 64 + (((schunk + 1) ^ sw) << 3)]) = vb1;
    __syncthreads();
#pragma unroll
    for (int ks = 0; ks < 2; ++ks) {
      short8 af[2], bfr[2];
#pragma unroll
      for (int mi = 0; mi < 2; ++mi) {
        const int r = wr + 16 * mi + lrow;
        af[mi] = *reinterpret_cast<const short8*>(
            &As[r * 64 + (((ks * 4 + lgrp) ^ (r & 7)) << 3)]);
      }
#pragma unroll
      for (int ni = 0; ni < 2; ++ni) {
        const int r = wc + 16 * ni + lrow;
        bfr[ni] = *reinterpret_cast<const short8*>(
            &Bs[r * 64 + (((ks * 4 + lgrp) ^ (r & 7)) << 3)]);
      }
#pragma unroll
      for (int mi = 0; mi < 2; ++mi)
#pragma unroll
        for (int ni = 0; ni < 2; ++ni)
          acc[mi][ni] = __builtin_amdgcn_mfma_f32_16x16x32_bf16(
              af[mi], bfr[ni], acc[mi][ni], 0, 0, 0);
    }
    __syncthreads();
  }
  // Epilogue: tu[row] = sum_n Y[row][n]*X[row+1][n], td with row-1.
  float tu[2][4] = {}, td[2][4] = {};
#pragma unroll
  for (int mi = 0; mi < 2; ++mi)
#pragma unroll
    for (int v = 0; v < 4; ++v) {
      const int grow = r0 + wr + 16 * mi + lgrp * 4 + v;
      const int sl = grow & (S - 1);
#pragma unroll
      for (int ni = 0; ni < 2; ++ni) {
        const int ncol = n0 + wc + 16 * ni + lrow;
        const float y = acc[mi][ni][v];
        if (sl < S - 1)
          tu[mi][v] += y * bf2f(Xb2[(size_t)(grow + 1) * D + ncol]);
        if (sl > 0)
          td[mi][v] += y * bf2f(Xb2[(size_t)(grow - 1) * D + ncol]);
      }
    }
#pragma unroll
  for (int m = 1; m <= 8; m <<= 1)
#pragma unroll
    for (int mi = 0; mi < 2; ++mi)
#pragma unroll
      for (int v = 0; v < 4; ++v) {
        tu[mi][v] += __shfl_xor(tu[mi][v], m, 64);
        td[mi][v] += __shfl_xor(td[mi][v], m, 64);
      }
  if (lrow == 0) {
    const int slot = blockIdx.y * 2 + (w & 1);
#pragma unroll
    for (int mi = 0; mi < 2; ++mi)
#pragma unroll
      for (int v = 0; v < 4; ++v) {
        const int grow = r0 + wr + 16 * mi + lgrp * 4 + v;
        g_tupart[slot][grow] = tu[mi][v];
        g_tdpart[slot][grow] = td[mi][v];
      }
  }
}

// ---------------- 5. fused partial-reduce + band softmax + scan ----------------
__global__ __launch_bounds__(1024) void k_smscan(const int* __restrict__ eos,
                                                 const float* __restrict__ prior) {
  const int b = blockIdx.x, s = threadIdx.x;
  const int idx = b * S + s;
  __shared__ float spp[S];
  __shared__ float wsum[16];
  float tuv = 0.f, tdv = 0.f;
#pragma unroll
  for (int p = 0; p < 16; ++p) {
    tuv += g_tupart[p][idx];
    tdv += g_tdpart[p][idx];
  }
  const float c = g_c0[0];
  const bool uv = (s + 1 < S) && (eos[b * S + s + 1] != 0);
  const bool dv = (s >= 1) && (eos[b * S + s - 1] != 0);
  const float su =
      uv ? (tuv + g_alpha[idx] + g_beta[idx + 1] + c) * (1.0f / 256.0f) : -1e9f;
  const float sd =
      dv ? (tdv + g_alpha[idx] + g_beta[idx - 1] + c) * (1.0f / 256.0f) : -1e9f;
  const float m = fmaxf(su, sd);
  const float eu = expf(su - m), ed = expf(sd - m);
  const float inv = 1.0f / (eu + ed);
  const float pn = eu * inv, pp = ed * inv;
  spp[s] = pp;
  __syncthreads();
  float v = 0.f, L = 0.f;
  if (s < S - 1) {
    v = sqrtf(pn * spp[s + 1] + 1e-9f);
    const float pr = prior[((size_t)b * S + s) * S + s + 1];
    L = logf(pr + (1.0f - pr) * v + 1e-9f);
  }
  g_nup[idx] = v;
  // shfl-based scan: C[s] = sum_{t<s} L[t]
  const int lane = s & 63, wid = s >> 6;
  float incl = L;
#pragma unroll
  for (int o = 1; o <= 32; o <<= 1) {
    const float t = __shfl_up(incl, o, 64);
    if (lane >= o) incl += t;
  }
  if (lane == 63) wsum[wid] = incl;
  __syncthreads();
  if (s < 16) {
    float x = wsum[s];
#pragma unroll
    for (int o = 1; o <= 8; o <<= 1) {
      const float t = __shfl_up(x, o, 16);
      if ((s & 15) >= o) x += t;
    }
    wsum[s] = x;
  }
  __syncthreads();
  g_C[idx] = incl - L + (wid ? wsum[wid - 1] : 0.0f);
}

// ---------------- 6. final outputs ----------------
__global__ __launch_bounds__(256) void k_final(const float* __restrict__ prior,
                                               float* __restrict__ out0,
                                               float* __restrict__ out1) {
  const int b = blockIdx.y, i = blockIdx.x, t = threadIdx.x;
  const size_t rowoff = ((size_t)b * S + i) * S;
  const float4 pr4 = reinterpret_cast<const float4*>(prior + rowoff)[t];
  const float4 cj4 = reinterpret_cast<const float4*>(g_C + b * S)[t];
  const float ci = g_C[b * S + i];
  const float SQ = sqrtf(1e-9f);
  const float prr[4] = {pr4.x, pr4.y, pr4.z, pr4.w};
  const float cjj[4] = {cj4.x, cj4.y, cj4.z, cj4.w};
  float o0[4], o1[4];
#pragma unroll
  for (int q = 0; q < 4; ++q) {
    const int j = t * 4 + q;
    const float p = prr[q];
    float v;
    if (j == i + 1) v = g_nup[b * S + i];
    else if (j == i - 1) v = g_nup[b * S + j];
    else v = SQ;
    o1[q] = p + (1.0f - p) * v;
    if (j == i) {
      o0[q] = p + (1.0f - p) * SQ;
    } else {
      const float d = (j > i) ? (cjj[q] - ci) : (ci - cjj[q]);
      o0[q] = expf(d) + 1e-9f;
    }
  }
  reinterpret_cast<float4*>(out0 + rowoff)[t] =
      make_float4(o0[0], o0[1], o0[2], o0[3]);
  reinterpret_cast<float4*>(out1 + rowoff)[t] =
      make_float4(o1[0], o1[1], o1[2], o1[3]);
}

extern "C" void kernel_launch(void* const* d_in, const int* in_sizes, int n_in,
                              void* d_out, int out_size, void* d_ws,
                              size_t ws_size, hipStream_t stream) {
  (void)in_sizes; (void)n_in; (void)out_size; (void)d_ws; (void)ws_size;
  const float* ctx = (const float*)d_in[0];
  const float* prior = (const float*)d_in[1];
  const float* Wq = (const float*)d_in[2];
  const float* bq = (const float*)d_in[3];
  const float* Wk = (const float*)d_in[4];
  const float* bk = (const float*)d_in[5];
  const float* gamma = (const float*)d_in[6];
  const float* beta = (const float*)d_in[7];
  const int* eos = (const int*)d_in[8];

  float* ob = (float*)d_out;
  float* out0 = ob;                      // [B,S,S]
  float* out1 = ob + (size_t)B * S * S;  // [B,S,S]
  // Scratch staged inside d_out; all consumed before k_final writes outputs.
  unsigned* Xb = (unsigned*)ob;          // bf16 X, 2M elems (floats [0,1M))
  ushort* Mt = (ushort*)(ob + 1048576);  // bf16 Mt = Wk@Wq^T (floats [1M,1.125M))

  k_bias<<<128, 256, 0, stream>>>(Wq, Wk, bq, bk);
  k_ln<<<B * S, 256, 0, stream>>>(ctx, gamma, beta, Xb);
  k_gemm_m<<<dim3(8, 8), 256, 0, stream>>>(Wk, Wq, Mt);
  k_banddot<<<dim3(64, 8), 256, 0, stream>>>((const ushort*)Xb, Mt);
  k_smscan<<<B, 1024, 0, stream>>>(eos, prior);
  k_final<<<dim3(S, B), 256, 0, stream>>>(prior, out0, out1);
}